// Round 1
// baseline (5536.808 us; speedup 1.0000x reference)
//
#include <hip/hip_runtime.h>
#include <cmath>

#define HH 512
#define WW 512
#define BB 8

// -------- workspace layout --------
// [0, 16)           : float scales[3]  (sw1, sw2, sw3)
// [1024, ...)       : float w1f[81*64]      dequantized conv1 weights, [tap][oc]
// [32768, ...)      : int8  w2q[64*25*32]   quantized conv2 weights, [ic][tap][oc]
// [131072, ...)     : int32 w3q[32*25]      quantized conv3 weights, [ic][tap]
// [1 MiB, +128 MiB) : uint8 h1[8][64][512][512]  quantized activations (q1)
// [next, +64 MiB)   : uint8 h2[8][32][512][512]  quantized activations (q2)
static constexpr size_t W1F_OFF = 1024;
static constexpr size_t W2Q_OFF = 32768;
static constexpr size_t W3Q_OFF = 131072;
static constexpr size_t H1_OFF  = (size_t)1 << 20;
static constexpr size_t H1_SZ   = (size_t)BB * 64 * HH * WW;      // 128 MiB
static constexpr size_t H2_OFF  = H1_OFF + H1_SZ;
static constexpr size_t H2_SZ   = (size_t)BB * 32 * HH * WW;      // 64 MiB
static constexpr size_t WS_NEED = H2_OFF + H2_SZ;

// -------- weight quantization: one block per tensor --------
__global__ void quant_weights_k(const float* __restrict__ w1,
                                const float* __restrict__ w2,
                                const float* __restrict__ w3,
                                float* __restrict__ scales,
                                float* __restrict__ w1f,
                                signed char* __restrict__ w2q,
                                int* __restrict__ w3q) {
  const int t = blockIdx.x;
  const float* src = (t == 0) ? w1 : (t == 1) ? w2 : w3;
  const int n = (t == 0) ? 64 * 81 : (t == 1) ? 32 * 64 * 25 : 32 * 25;
  __shared__ float red[256];
  float m = 0.0f;
  for (int i = threadIdx.x; i < n; i += 256) m = fmaxf(m, fabsf(src[i]));
  red[threadIdx.x] = m;
  __syncthreads();
  for (int s = 128; s > 0; s >>= 1) {
    if ((int)threadIdx.x < s) red[threadIdx.x] = fmaxf(red[threadIdx.x], red[threadIdx.x + s]);
    __syncthreads();
  }
  const float scale = red[0] / 127.0f;   // qmax = 2^(8-1)-1 = 127 for all three
  if (threadIdx.x == 0) scales[t] = scale;
  for (int i = threadIdx.x; i < n; i += 256) {
    float q = rintf(src[i] / scale);
    q = fminf(fmaxf(q, -127.0f), 127.0f);
    if (t == 0) {
      // w1 is (64,1,9,9): i = oc*81 + tap  ->  [tap][oc], dequantized fp32
      const int oc = i / 81, tap = i - oc * 81;
      w1f[tap * 64 + oc] = q * scale;
    } else if (t == 1) {
      // w2 is (32,64,5,5): i = (oc*64+ic)*25 + tap  ->  [ic][tap][oc], int8
      const int oc = i / 1600;
      const int r = i - oc * 1600;
      const int ic = r / 25, tap = r - ic * 25;
      w2q[(ic * 25 + tap) * 32 + oc] = (signed char)(int)q;
    } else {
      // w3 is (1,32,5,5): i = ic*25 + tap  ->  [ic][tap], int32 (unpacked)
      w3q[i] = (int)q;
    }
  }
}

// -------- conv1: 1->64, k=9, pad=4, fp32 x * dequantized w, quant-ReLU -> uint8 --------
__global__ __launch_bounds__(256) void conv1_k(
    const float* __restrict__ x, const float* __restrict__ w1f,
    const float* __restrict__ b1, const float* __restrict__ s1,
    unsigned char* __restrict__ h1) {
  const int p  = blockIdx.x * 256 + threadIdx.x;
  const int px = p % WW;
  const int py = (p / WW) % HH;
  const int b  = p / (WW * HH);

  float acc[64];
  #pragma unroll
  for (int oc = 0; oc < 64; ++oc) acc[oc] = b1[oc];

  const float* xb = x + (size_t)b * (HH * WW);
  for (int ky = 0; ky < 9; ++ky) {
    const int yy = py + ky - 4;
    if (yy < 0 || yy >= HH) continue;
    for (int kx = 0; kx < 9; ++kx) {
      const int xx = px + kx - 4;
      if (xx < 0 || xx >= WW) continue;
      const float xv = xb[yy * WW + xx];
      const float* wr = w1f + (ky * 9 + kx) * 64;
      #pragma unroll
      for (int oc = 0; oc < 64; ++oc) acc[oc] = fmaf(xv, wr[oc], acc[oc]);
    }
  }

  const float sc = s1[0];
  const float step = sc / 255.0f;
  #pragma unroll
  for (int oc = 0; oc < 64; ++oc) {
    const float c = fminf(fmaxf(acc[oc], 0.0f), sc);
    int qi = (int)rintf(c / step);
    qi = qi < 0 ? 0 : (qi > 255 ? 255 : qi);
    h1[(((size_t)b * 64 + oc) * HH + py) * WW + px] = (unsigned char)qi;
  }
}

// -------- conv2: 64->32, k=5, pad=2, exact int arithmetic, quant-ReLU -> uint8 --------
__global__ __launch_bounds__(256) void conv2_k(
    const unsigned char* __restrict__ h1, const signed char* __restrict__ w2q,
    const float* __restrict__ b2, const float* __restrict__ scales,
    const float* __restrict__ s1, const float* __restrict__ s2,
    unsigned char* __restrict__ h2) {
  const int p  = blockIdx.x * 256 + threadIdx.x;
  const int px = p % WW;
  const int py = (p / WW) % HH;
  const int b  = p / (WW * HH);

  int acc[32];
  #pragma unroll
  for (int oc = 0; oc < 32; ++oc) acc[oc] = 0;

  const int y0 = py - 2, x0 = px - 2;
  for (int ic = 0; ic < 64; ++ic) {
    const unsigned char* hb = h1 + ((size_t)b * 64 + ic) * (HH * WW);
    for (int ky = 0; ky < 5; ++ky) {
      const int yy = y0 + ky;
      if (yy < 0 || yy >= HH) continue;
      for (int kx = 0; kx < 5; ++kx) {
        const int xx = x0 + kx;
        if (xx < 0 || xx >= WW) continue;
        const int a = hb[yy * WW + xx];
        // weights: 32 int8 packed in 8 dwords, uniform address -> hope for s_load
        const int* wr = (const int*)(w2q + ((size_t)(ic * 25 + ky * 5 + kx) << 5));
        #pragma unroll
        for (int g = 0; g < 8; ++g) {
          const int wp = wr[g];
          acc[g * 4 + 0] += a * ((wp << 24) >> 24);
          acc[g * 4 + 1] += a * ((wp << 16) >> 24);
          acc[g * 4 + 2] += a * ((wp << 8) >> 24);
          acc[g * 4 + 3] += a * (wp >> 24);
        }
      }
    }
  }

  const float step1 = s1[0] / 255.0f;
  const float sc2 = s2[0];
  const float step2 = sc2 / 255.0f;
  const float asc = step1 * scales[1];   // (q1*qw) * step1 * sw2
  #pragma unroll
  for (int oc = 0; oc < 32; ++oc) {
    const float y = (float)acc[oc] * asc + b2[oc];
    const float c = fminf(fmaxf(y, 0.0f), sc2);
    int qi = (int)rintf(c / step2);
    qi = qi < 0 ? 0 : (qi > 255 ? 255 : qi);
    h2[(((size_t)b * 32 + oc) * HH + py) * WW + px] = (unsigned char)qi;
  }
}

// -------- conv3: 32->1, k=5, pad=2, exact int arithmetic, quant-ReLU -> fp32 out --------
__global__ __launch_bounds__(256) void conv3_k(
    const unsigned char* __restrict__ h2, const int* __restrict__ w3q,
    const float* __restrict__ b3, const float* __restrict__ scales,
    const float* __restrict__ s2, const float* __restrict__ s3,
    float* __restrict__ out) {
  const int p  = blockIdx.x * 256 + threadIdx.x;
  const int px = p % WW;
  const int py = (p / WW) % HH;
  const int b  = p / (WW * HH);

  int acc = 0;
  for (int ic = 0; ic < 32; ++ic) {
    const unsigned char* hb = h2 + ((size_t)b * 32 + ic) * (HH * WW);
    const int* wr = w3q + ic * 25;
    for (int ky = 0; ky < 5; ++ky) {
      const int yy = py + ky - 2;
      if (yy < 0 || yy >= HH) continue;
      #pragma unroll
      for (int kx = 0; kx < 5; ++kx) {
        const int xx = px + kx - 2;
        if (xx < 0 || xx >= WW) continue;
        acc += (int)hb[yy * WW + xx] * wr[ky * 5 + kx];
      }
    }
  }

  const float step2 = s2[0] / 255.0f;
  const float sc3 = s3[0];
  const float step3 = sc3 / 255.0f;
  const float y = (float)acc * (step2 * scales[2]) + b3[0];
  const float c = fminf(fmaxf(y, 0.0f), sc3);
  float q = rintf(c / step3);
  q = fminf(fmaxf(q, 0.0f), 255.0f);
  out[p] = q * step3;
}

extern "C" void kernel_launch(void* const* d_in, const int* in_sizes, int n_in,
                              void* d_out, int out_size, void* d_ws, size_t ws_size,
                              hipStream_t stream) {
  const float* x  = (const float*)d_in[0];
  const float* w1 = (const float*)d_in[1];
  const float* b1 = (const float*)d_in[2];
  const float* w2 = (const float*)d_in[3];
  const float* b2 = (const float*)d_in[4];
  const float* w3 = (const float*)d_in[5];
  const float* b3 = (const float*)d_in[6];
  const float* s1 = (const float*)d_in[7];
  const float* s2 = (const float*)d_in[8];
  const float* s3 = (const float*)d_in[9];

  if (ws_size < WS_NEED) return;  // workspace too small — fail visibly rather than corrupt

  char* ws = (char*)d_ws;
  float*       scales = (float*)ws;
  float*       w1f    = (float*)(ws + W1F_OFF);
  signed char* w2q    = (signed char*)(ws + W2Q_OFF);
  int*         w3q    = (int*)(ws + W3Q_OFF);
  unsigned char* h1   = (unsigned char*)(ws + H1_OFF);
  unsigned char* h2   = (unsigned char*)(ws + H2_OFF);

  quant_weights_k<<<3, 256, 0, stream>>>(w1, w2, w3, scales, w1f, w2q, w3q);

  const int npix = BB * HH * WW;           // 2,097,152
  conv1_k<<<npix / 256, 256, 0, stream>>>(x, w1f, b1, s1, h1);
  conv2_k<<<npix / 256, 256, 0, stream>>>(h1, w2q, b2, scales, s1, s2, h2);
  conv3_k<<<npix / 256, 256, 0, stream>>>(h2, w3q, b3, scales, s2, s3, (float*)d_out);
}

// Round 2
// 679.307 us; speedup vs baseline: 8.1507x; 8.1507x over previous
//
#include <hip/hip_runtime.h>
#include <cmath>

#define HH 512
#define WW 512
#define BB 8
#define WP (WW + 4)   // padded row width (2-px halo each side)

typedef int v4i __attribute__((ext_vector_type(4)));

// -------- sdot4: u8-biased-i8 dot helper --------
#if defined(__has_builtin)
#if __has_builtin(__builtin_amdgcn_sdot4)
#define DOT4(a, b, c) __builtin_amdgcn_sdot4((a), (b), (c), false)
#endif
#endif
#ifndef DOT4
static __device__ __forceinline__ int dot4_fb(int a, int b, int c) {
  c += ((a << 24) >> 24) * ((b << 24) >> 24);
  c += ((a << 16) >> 24) * ((b << 16) >> 24);
  c += ((a << 8) >> 24) * ((b << 8) >> 24);
  c += (a >> 24) * (b >> 24);
  return c;
}
#define DOT4(a, b, c) dot4_fb((a), (b), (c))
#endif

// -------- workspace layout --------
// scales[3] f32 | corr2[5][32] i32 | rowsum3[5] i32 | w1f[81][64] f32
// w2s[25][4][32][16] i8 (MFMA-B layout) | w3p[25][32] i8
// h1p: u8 [B][H][W+4][64]  (value = q1-128, halo = 0x80)
// h2p: u8 [B][H][W+4][32]  (value = q2-128, halo = 0x80)
static constexpr size_t SCALES_OFF = 0;
static constexpr size_t CORR2_OFF  = 64;
static constexpr size_t RS3_OFF    = 768;
static constexpr size_t W1F_OFF    = 1024;
static constexpr size_t W2S_OFF    = 32768;
static constexpr size_t W3P_OFF    = 90112;
static constexpr size_t H1_OFF     = (size_t)1 << 20;
static constexpr size_t H1_SZ      = (size_t)BB * HH * WP * 64;   // ~129 MiB
static constexpr size_t H2_OFF     = H1_OFF + H1_SZ;
static constexpr size_t H2_SZ      = (size_t)BB * HH * WP * 32;   // ~64.5 MiB
static constexpr size_t WS_NEED    = H2_OFF + H2_SZ;

// -------- weight quantization --------
__global__ void quant_weights_k(const float* __restrict__ w1,
                                const float* __restrict__ w2,
                                const float* __restrict__ w3,
                                float* __restrict__ scales,
                                float* __restrict__ w1f,
                                signed char* __restrict__ w2s,
                                signed char* __restrict__ w3p) {
  const int t = blockIdx.x;
  const float* src = (t == 0) ? w1 : (t == 1) ? w2 : w3;
  const int n = (t == 0) ? 64 * 81 : (t == 1) ? 32 * 64 * 25 : 32 * 25;
  __shared__ float red[256];
  float m = 0.0f;
  for (int i = threadIdx.x; i < n; i += 256) m = fmaxf(m, fabsf(src[i]));
  red[threadIdx.x] = m;
  __syncthreads();
  for (int s = 128; s > 0; s >>= 1) {
    if ((int)threadIdx.x < s) red[threadIdx.x] = fmaxf(red[threadIdx.x], red[threadIdx.x + s]);
    __syncthreads();
  }
  const float scale = red[0] / 127.0f;
  if (threadIdx.x == 0) scales[t] = scale;
  for (int i = threadIdx.x; i < n; i += 256) {
    float q = rintf(src[i] / scale);
    q = fminf(fmaxf(q, -127.0f), 127.0f);
    if (t == 0) {
      const int oc = i / 81, tap = i - oc * 81;
      w1f[tap * 64 + oc] = q * scale;
    } else if (t == 1) {
      // w2 (oc=32, ic=64, 5, 5) -> [tap][kb=ic>>4][oc][j=ic&15]
      const int oc = i / 1600;
      const int r = i - oc * 1600;
      const int ic = r / 25, tap = r - ic * 25;
      w2s[(((tap * 4 + (ic >> 4)) * 32) + oc) * 16 + (ic & 15)] = (signed char)(int)q;
    } else {
      // w3 (1, ic=32, 5, 5) -> [tap][ic]
      const int ic = i / 25, tap = i - ic * 25;
      w3p[tap * 32 + ic] = (signed char)(int)q;
    }
  }
}

// -------- corrections: corr2[ky][oc] = sum_kx,ic w2 ; rowsum3[ky] = sum_kx,ic w3 --------
__global__ void prep_k(const signed char* __restrict__ w2s,
                       const signed char* __restrict__ w3p,
                       int* __restrict__ corr2, int* __restrict__ rowsum3) {
  const int tid = threadIdx.x;
  if (tid < 160) {
    const int ky = tid >> 5, oc = tid & 31;
    int s = 0;
    for (int kx = 0; kx < 5; ++kx)
      for (int kb = 0; kb < 4; ++kb)
        for (int j = 0; j < 16; ++j)
          s += (int)w2s[(((ky * 5 + kx) * 4 + kb) * 32 + oc) * 16 + j];
    corr2[tid] = s;
  } else if (tid < 165) {
    const int ky = tid - 160;
    int s = 0;
    for (int kx = 0; kx < 5; ++kx)
      for (int ic = 0; ic < 32; ++ic)
        s += (int)w3p[(ky * 5 + kx) * 32 + ic];
    rowsum3[ky] = s;
  }
}

// -------- fill x-halo columns with 0x80 (biased zero) --------
__global__ void fill_k(unsigned char* __restrict__ h1p, unsigned char* __restrict__ h2p) {
  const int idx = blockIdx.x * 256 + threadIdx.x;
  const uint4 v = make_uint4(0x80808080u, 0x80808080u, 0x80808080u, 0x80808080u);
  if (idx < 65536) {         // h1p: 4096 rows x 4 cols x 4 uint4
    const int rowi = idx >> 4, r = idx & 15, c4 = r >> 2, q = r & 3;
    const int c = (c4 < 2) ? c4 : (WW + c4);
    *(uint4*)(h1p + ((size_t)rowi * WP + c) * 64 + q * 16) = v;
  } else {                   // h2p: 4096 rows x 4 cols x 2 uint4
    const int e = idx - 65536;
    const int rowi = e >> 3, r = e & 7, c4 = r >> 1, q = r & 1;
    const int c = (c4 < 2) ? c4 : (WW + c4);
    *(uint4*)(h2p + ((size_t)rowi * WP + c) * 32 + q * 16) = v;
  }
}

// -------- conv1: fp32 VALU, writes biased u8 NHWC padded --------
__global__ __launch_bounds__(256) void conv1_k(
    const float* __restrict__ x, const float* __restrict__ w1f,
    const float* __restrict__ b1, const float* __restrict__ s1,
    unsigned char* __restrict__ h1p) {
  const int p  = blockIdx.x * 256 + threadIdx.x;
  const int px = p & (WW - 1);
  const int py = (p >> 9) & (HH - 1);
  const int bz = p >> 18;

  float acc[64];
  #pragma unroll
  for (int oc = 0; oc < 64; ++oc) acc[oc] = b1[oc];

  const float* xb = x + (size_t)bz * (HH * WW);
  for (int ky = 0; ky < 9; ++ky) {
    const int yy = py + ky - 4;
    if (yy < 0 || yy >= HH) continue;
    const float* xr = xb + (size_t)yy * WW;
    for (int kx = 0; kx < 9; ++kx) {
      const int xx = px + kx - 4;
      if (xx < 0 || xx >= WW) continue;
      const float xv = xr[xx];
      const float* wr = w1f + (ky * 9 + kx) * 64;
      #pragma unroll
      for (int oc = 0; oc < 64; ++oc) acc[oc] = fmaf(xv, wr[oc], acc[oc]);
    }
  }

  const float sc = s1[0];
  const float step = sc / 255.0f;
  unsigned int dw[16];
  #pragma unroll
  for (int g = 0; g < 16; ++g) {
    unsigned int d = 0;
    #pragma unroll
    for (int j = 0; j < 4; ++j) {
      const float c = fminf(fmaxf(acc[g * 4 + j], 0.0f), sc);
      int qi = (int)rintf(c / step);
      qi = qi < 0 ? 0 : (qi > 255 ? 255 : qi);
      d |= (unsigned int)(qi ^ 0x80) << (8 * j);
    }
    dw[g] = d;
  }
  uint4* dst = (uint4*)(h1p + (((size_t)(bz * HH + py)) * WP + px + 2) * 64);
  #pragma unroll
  for (int g = 0; g < 4; ++g)
    dst[g] = make_uint4(dw[4 * g], dw[4 * g + 1], dw[4 * g + 2], dw[4 * g + 3]);
}

// -------- conv2: implicit-GEMM int8 MFMA --------
// block = 256 px of one row (2 blocks/row); wave = 64 px x 32 oc
// A: M=16 px, K=64 ic (per tap); lane: row=l&15, kb=l>>4 -> 16B contiguous ic
// B: [tap][kb][oc][16] in LDS; D: col(oc)=l&15, pixrow=(l>>4)*4+reg
__global__ __launch_bounds__(256) void conv2_k(
    const unsigned char* __restrict__ h1p,
    const int4* __restrict__ w2s,
    const int* __restrict__ corr2,
    const float* __restrict__ b2,
    const float* __restrict__ scales,
    const float* __restrict__ s1, const float* __restrict__ s2,
    unsigned char* __restrict__ h2p) {
  __shared__ alignas(16) signed char wlds[51200];
  __shared__ int clds[160];
  {
    int4* dst = (int4*)wlds;
    for (int i = threadIdx.x; i < 3200; i += 256) dst[i] = w2s[i];
    if (threadIdx.x < 160) clds[threadIdx.x] = corr2[threadIdx.x];
  }
  __syncthreads();

  const int lane = threadIdx.x & 63;
  const int wave = threadIdx.x >> 6;
  const int y = blockIdx.y, bz = blockIdx.z;
  const int xw = blockIdx.x * 256 + wave * 64;
  const int row = lane & 15, kb = lane >> 4;

  v4i acc[4][2];
  #pragma unroll
  for (int t = 0; t < 4; ++t)
    #pragma unroll
    for (int n = 0; n < 2; ++n) acc[t][n] = (v4i){0, 0, 0, 0};

  const size_t a_lane_off = (size_t)(xw + row) * 64 + kb * 16;
  const signed char* bl = wlds + kb * 512 + row * 16;

  #pragma unroll
  for (int ky = 0; ky < 5; ++ky) {
    const int yy = y + ky - 2;
    if (yy < 0 || yy >= HH) continue;  // wave-uniform skip
    const unsigned char* ap = h1p + ((size_t)(bz * HH + yy) * WP) * 64 + a_lane_off;
    const signed char* bt = bl + (ky * 5) * 2048;
    #pragma unroll
    for (int kx = 0; kx < 5; ++kx) {
      const v4i a0 = *(const v4i*)(ap + kx * 64);
      const v4i a1 = *(const v4i*)(ap + kx * 64 + 1024);
      const v4i a2 = *(const v4i*)(ap + kx * 64 + 2048);
      const v4i a3 = *(const v4i*)(ap + kx * 64 + 3072);
      const v4i bf0 = *(const v4i*)(bt + kx * 2048);
      const v4i bf1 = *(const v4i*)(bt + kx * 2048 + 256);
      acc[0][0] = __builtin_amdgcn_mfma_i32_16x16x64_i8(a0, bf0, acc[0][0], 0, 0, 0);
      acc[0][1] = __builtin_amdgcn_mfma_i32_16x16x64_i8(a0, bf1, acc[0][1], 0, 0, 0);
      acc[1][0] = __builtin_amdgcn_mfma_i32_16x16x64_i8(a1, bf0, acc[1][0], 0, 0, 0);
      acc[1][1] = __builtin_amdgcn_mfma_i32_16x16x64_i8(a1, bf1, acc[1][1], 0, 0, 0);
      acc[2][0] = __builtin_amdgcn_mfma_i32_16x16x64_i8(a2, bf0, acc[2][0], 0, 0, 0);
      acc[2][1] = __builtin_amdgcn_mfma_i32_16x16x64_i8(a2, bf1, acc[2][1], 0, 0, 0);
      acc[3][0] = __builtin_amdgcn_mfma_i32_16x16x64_i8(a3, bf0, acc[3][0], 0, 0, 0);
      acc[3][1] = __builtin_amdgcn_mfma_i32_16x16x64_i8(a3, bf1, acc[3][1], 0, 0, 0);
    }
  }

  // per-oc bias correction for the signed-shift: +128 * sum_w over included taps
  int corr[2] = {0, 0};
  #pragma unroll
  for (int ky = 0; ky < 5; ++ky) {
    const int yy = y + ky - 2;
    if (yy >= 0 && yy < HH) {
      corr[0] += clds[ky * 32 + row];
      corr[1] += clds[ky * 32 + 16 + row];
    }
  }

  const float step1 = s1[0] / 255.0f;
  const float sc2 = s2[0], step2 = sc2 / 255.0f;
  const float asc = step1 * scales[1];
  unsigned char* orow = h2p + ((size_t)(bz * HH + y) * WP + 2) * 32;
  #pragma unroll
  for (int t = 0; t < 4; ++t) {
    #pragma unroll
    for (int n = 0; n < 2; ++n) {
      const int oc = n * 16 + row;
      const float bias = b2[oc];
      #pragma unroll
      for (int r = 0; r < 4; ++r) {
        const int pix = xw + t * 16 + kb * 4 + r;
        const float v = (float)(acc[t][n][r] + corr[n] * 128) * asc + bias;
        const float c = fminf(fmaxf(v, 0.0f), sc2);
        int qi = (int)rintf(c / step2);
        qi = qi < 0 ? 0 : (qi > 255 ? 255 : qi);
        orow[(size_t)pix * 32 + oc] = (unsigned char)(qi ^ 0x80);
      }
    }
  }
}

// -------- conv3: NHWC + sdot4, exact int --------
__global__ __launch_bounds__(256) void conv3_k(
    const unsigned char* __restrict__ h2p,
    const signed char* __restrict__ w3p,
    const int* __restrict__ rowsum3,
    const float* __restrict__ b3,
    const float* __restrict__ scales,
    const float* __restrict__ s2, const float* __restrict__ s3,
    float* __restrict__ out) {
  const int p  = blockIdx.x * 256 + threadIdx.x;
  const int px = p & (WW - 1);
  const int py = (p >> 9) & (HH - 1);
  const int bz = p >> 18;

  int acc = 0, corr = 0;
  #pragma unroll
  for (int ky = 0; ky < 5; ++ky) {
    const int yy = py + ky - 2;
    if (yy < 0 || yy >= HH) continue;
    corr += rowsum3[ky];
    const unsigned char* rp = h2p + ((size_t)(bz * HH + yy) * WP + px) * 32;
    #pragma unroll
    for (int kx = 0; kx < 5; ++kx) {
      const int* ap = (const int*)(rp + kx * 32);
      const int* wp = (const int*)(w3p + (ky * 5 + kx) * 32);
      #pragma unroll
      for (int g = 0; g < 8; ++g) acc = DOT4(ap[g], wp[g], acc);
    }
  }

  const int tot = acc + corr * 128;
  const float step2 = s2[0] / 255.0f;
  const float sc3 = s3[0], step3 = sc3 / 255.0f;
  const float y = (float)tot * (step2 * scales[2]) + b3[0];
  const float c = fminf(fmaxf(y, 0.0f), sc3);
  float q = rintf(c / step3);
  q = fminf(fmaxf(q, 0.0f), 255.0f);
  out[p] = q * step3;
}

extern "C" void kernel_launch(void* const* d_in, const int* in_sizes, int n_in,
                              void* d_out, int out_size, void* d_ws, size_t ws_size,
                              hipStream_t stream) {
  const float* x  = (const float*)d_in[0];
  const float* w1 = (const float*)d_in[1];
  const float* b1 = (const float*)d_in[2];
  const float* w2 = (const float*)d_in[3];
  const float* b2 = (const float*)d_in[4];
  const float* w3 = (const float*)d_in[5];
  const float* b3 = (const float*)d_in[6];
  const float* s1 = (const float*)d_in[7];
  const float* s2 = (const float*)d_in[8];
  const float* s3 = (const float*)d_in[9];

  if (ws_size < WS_NEED) return;

  char* ws = (char*)d_ws;
  float*       scales  = (float*)(ws + SCALES_OFF);
  int*         corr2   = (int*)(ws + CORR2_OFF);
  int*         rowsum3 = (int*)(ws + RS3_OFF);
  float*       w1f     = (float*)(ws + W1F_OFF);
  signed char* w2s     = (signed char*)(ws + W2S_OFF);
  signed char* w3p     = (signed char*)(ws + W3P_OFF);
  unsigned char* h1p   = (unsigned char*)(ws + H1_OFF);
  unsigned char* h2p   = (unsigned char*)(ws + H2_OFF);

  quant_weights_k<<<3, 256, 0, stream>>>(w1, w2, w3, scales, w1f, w2s, w3p);
  prep_k<<<1, 256, 0, stream>>>(w2s, w3p, corr2, rowsum3);
  fill_k<<<384, 256, 0, stream>>>(h1p, h2p);

  const int npix = BB * HH * WW;
  conv1_k<<<npix / 256, 256, 0, stream>>>(x, w1f, b1, s1, h1p);
  dim3 g2(2, HH, BB);
  conv2_k<<<g2, 256, 0, stream>>>(h1p, (const int4*)w2s, corr2, b2, scales, s1, s2, h2p);
  conv3_k<<<npix / 256, 256, 0, stream>>>(h2p, w3p, rowsum3, b3, scales, s2, s3, (float*)d_out);
}

// Round 3
// 551.748 us; speedup vs baseline: 10.0350x; 1.2312x over previous
//
#include <hip/hip_runtime.h>
#include <cmath>

#define HH 512
#define WW 512
#define BB 8
#define WP (WW + 4)   // padded row width for h1p/h2p (2-px halo each side)

#define PROWS 520     // x-plane rows: 512 + 4 top + 4 bottom
#define PCOLS 528     // x-plane cols: 512 + 4 left + 12 right (kx pad to 16)
#define PT ((size_t)BB * PROWS * PCOLS)   // elems per plane: 2,196,480

typedef int v4i __attribute__((ext_vector_type(4)));
typedef float v4f __attribute__((ext_vector_type(4)));
typedef _Float16 v8h __attribute__((ext_vector_type(8)));

// -------- sdot4 helper (conv3) --------
#if defined(__has_builtin)
#if __has_builtin(__builtin_amdgcn_sdot4)
#define DOT4(a, b, c) __builtin_amdgcn_sdot4((a), (b), (c), false)
#endif
#endif
#ifndef DOT4
static __device__ __forceinline__ int dot4_fb(int a, int b, int c) {
  c += ((a << 24) >> 24) * ((b << 24) >> 24);
  c += ((a << 16) >> 24) * ((b << 16) >> 24);
  c += ((a << 8) >> 24) * ((b << 8) >> 24);
  c += (a >> 24) * (b >> 24);
  return c;
}
#define DOT4(a, b, c) dot4_fb((a), (b), (c))
#endif

// -------- workspace layout --------
static constexpr size_t SCALES_OFF = 0;        // float[3]
static constexpr size_t CORR2_OFF  = 64;       // int[160]
static constexpr size_t RS3_OFF    = 768;      // int[5]
static constexpr size_t QW1_OFF    = 1024;     // float[64*81] raw q for w1
static constexpr size_t W1FRAG_OFF = 24576;    // f16[9*4*64*8] MFMA-B frags (36864 B)
static constexpr size_t W2S_OFF    = 65536;    // i8[25*4*32*16]
static constexpr size_t W3P_OFF    = 131072;   // i8[25*32]
static constexpr size_t H1_OFF     = (size_t)1 << 20;
static constexpr size_t H1_SZ      = (size_t)BB * HH * WP * 64;
static constexpr size_t H2_OFF     = H1_OFF + H1_SZ;
static constexpr size_t H2_SZ      = (size_t)BB * HH * WP * 32;
static constexpr size_t WS_NEED    = H2_OFF + H2_SZ;
// x-planes (4 * PT f16 = 17.6 MB) live in the h2p region until conv2 runs.

// -------- weight quantization --------
__global__ void quant_weights_k(const float* __restrict__ w1,
                                const float* __restrict__ w2,
                                const float* __restrict__ w3,
                                float* __restrict__ scales,
                                float* __restrict__ qw1,
                                signed char* __restrict__ w2s,
                                signed char* __restrict__ w3p) {
  const int t = blockIdx.x;
  const float* src = (t == 0) ? w1 : (t == 1) ? w2 : w3;
  const int n = (t == 0) ? 64 * 81 : (t == 1) ? 32 * 64 * 25 : 32 * 25;
  __shared__ float red[256];
  float m = 0.0f;
  for (int i = threadIdx.x; i < n; i += 256) m = fmaxf(m, fabsf(src[i]));
  red[threadIdx.x] = m;
  __syncthreads();
  for (int s = 128; s > 0; s >>= 1) {
    if ((int)threadIdx.x < s) red[threadIdx.x] = fmaxf(red[threadIdx.x], red[threadIdx.x + s]);
    __syncthreads();
  }
  const float scale = red[0] / 127.0f;
  if (threadIdx.x == 0) scales[t] = scale;
  for (int i = threadIdx.x; i < n; i += 256) {
    float q = rintf(src[i] / scale);
    q = fminf(fmaxf(q, -127.0f), 127.0f);
    if (t == 0) {
      qw1[i] = q;                                    // raw integer value as float, [oc][tap]
    } else if (t == 1) {
      const int oc = i / 1600;
      const int r = i - oc * 1600;
      const int ic = r / 25, tap = r - ic * 25;
      w2s[(((tap * 4 + (ic >> 4)) * 32) + oc) * 16 + (ic & 15)] = (signed char)(int)q;
    } else {
      const int ic = i / 25, tap = i - ic * 25;
      w3p[tap * 32 + ic] = (signed char)(int)q;
    }
  }
}

// -------- prep: corr2 / rowsum3 / conv1 B-fragments --------
__global__ void prep_k(const signed char* __restrict__ w2s,
                       const signed char* __restrict__ w3p,
                       const float* __restrict__ qw1,
                       int* __restrict__ corr2, int* __restrict__ rowsum3,
                       unsigned short* __restrict__ w1frag) {
  const int tid = threadIdx.x;
  if (tid < 160) {
    const int ky = tid >> 5, oc = tid & 31;
    int s = 0;
    for (int kx = 0; kx < 5; ++kx)
      for (int kb = 0; kb < 4; ++kb)
        for (int j = 0; j < 16; ++j)
          s += (int)w2s[(((ky * 5 + kx) * 4 + kb) * 32 + oc) * 16 + j];
    corr2[tid] = s;
  } else if (tid < 165) {
    const int ky = tid - 160;
    int s = 0;
    for (int kx = 0; kx < 5; ++kx)
      for (int ic = 0; ic < 32; ++ic)
        s += (int)w3p[(ky * 5 + kx) * 32 + ic];
    rowsum3[ky] = s;
  }
  // conv1 B-frags: [j=0..8][n=0..3][lane=0..63][e=0..7], tap t = 32j + (lane>>4)*8 + e
  // t = term*144 + ky*16 + kx ; weight = q[oc][ky][kx] (0 if kx>=9), term1 scaled 1/4096
  for (int i = tid; i < 18432; i += 256) {
    const int e = i & 7, lidx = (i >> 3) & 63, nn = (i >> 9) & 3, j = i >> 11;
    const int t = j * 32 + (lidx >> 4) * 8 + e;
    const int term = (t >= 144) ? 1 : 0;
    const int rem = t - term * 144;
    const int ky = rem >> 4, kx = rem & 15;
    const int oc = nn * 16 + (lidx & 15);
    float v = 0.0f;
    if (kx < 9) v = qw1[oc * 81 + ky * 9 + kx];
    if (term) v *= (1.0f / 4096.0f);
    const _Float16 hv = (_Float16)v;
    w1frag[i] = __builtin_bit_cast(unsigned short, hv);
  }
}

// -------- prep x-planes: f16 hi/lo split, zero-padded, parity-duplicated --------
// planes[par][term][b][row][col]; par1 shifted left one px (P1[c] = P0[c+1])
__global__ __launch_bounds__(256) void prep_x_k(const float* __restrict__ x,
                                                unsigned short* __restrict__ planes) {
  const size_t i = (size_t)blockIdx.x * 256 + threadIdx.x;
  if (i >= PT) return;
  const int col = (int)(i % PCOLS);
  const size_t t = i / PCOLS;
  const int row = (int)(t % PROWS);
  const int b = (int)(t / PROWS);
  const float* xb = x + (size_t)b * HH * WW;
  const int xr = row - 4;
  float v0 = 0.0f, v1 = 0.0f;
  if (xr >= 0 && xr < HH) {
    const int c0 = col - 4, c1 = col - 3;
    if (c0 >= 0 && c0 < WW) v0 = xb[(size_t)xr * WW + c0];
    if (c1 >= 0 && c1 < WW) v1 = xb[(size_t)xr * WW + c1];
  }
  const _Float16 h0 = (_Float16)v0;
  const _Float16 l0 = (_Float16)((v0 - (float)h0) * 4096.0f);
  const _Float16 h1 = (_Float16)v1;
  const _Float16 l1 = (_Float16)((v1 - (float)h1) * 4096.0f);
  planes[i]          = __builtin_bit_cast(unsigned short, h0);
  planes[PT + i]     = __builtin_bit_cast(unsigned short, l0);
  planes[2 * PT + i] = __builtin_bit_cast(unsigned short, h1);
  planes[3 * PT + i] = __builtin_bit_cast(unsigned short, l1);
}

// -------- fill x-halo columns of h1p/h2p with 0x80 (biased zero) --------
__global__ void fill_k(unsigned char* __restrict__ h1p, unsigned char* __restrict__ h2p) {
  const int idx = blockIdx.x * 256 + threadIdx.x;
  const uint4 v = make_uint4(0x80808080u, 0x80808080u, 0x80808080u, 0x80808080u);
  if (idx < 65536) {
    const int rowi = idx >> 4, r = idx & 15, c4 = r >> 2, q = r & 3;
    const int c = (c4 < 2) ? c4 : (WW + c4);
    *(uint4*)(h1p + ((size_t)rowi * WP + c) * 64 + q * 16) = v;
  } else {
    const int e = idx - 65536;
    const int rowi = e >> 3, r = e & 7, c4 = r >> 1, q = r & 1;
    const int c = (c4 < 2) ? c4 : (WW + c4);
    *(uint4*)(h2p + ((size_t)rowi * WP + c) * 32 + q * 1 * 16) = v;
  }
}

// -------- conv1: f16-split implicit-GEMM MFMA (exact), writes biased u8 NHWC --------
// block = 1 row (512 px), 8 waves x 64 px; wave tile 64 px x 64 oc, K = 288
__global__ __launch_bounds__(512) void conv1_k(
    const unsigned short* __restrict__ planes,
    const unsigned short* __restrict__ w1frag,
    const float* __restrict__ b1,
    const float* __restrict__ scales,
    const float* __restrict__ s1,
    unsigned char* __restrict__ h1p) {
  __shared__ alignas(16) unsigned short wf[18432];
  for (int i = threadIdx.x; i < 2304; i += 512)
    ((int4*)wf)[i] = ((const int4*)w1frag)[i];
  __syncthreads();

  const int y = blockIdx.x & (HH - 1);
  const int b = blockIdx.x >> 9;
  const int l = threadIdx.x & 63;
  const int wv = threadIdx.x >> 6;
  const int pxw = wv * 64;
  const int r = l & 15, kb = l >> 4;

  // parity-selected base: even-px lanes read P0, odd-px lanes read P1 (pre-shifted)
  const unsigned short* pb = planes + (size_t)(r & 1) * (2 * PT)
                           + ((size_t)b * PROWS + y) * PCOLS + (pxw + (r & ~1));
  int offs[9];
  #pragma unroll
  for (int j = 0; j < 9; ++j) {
    const int t0 = j * 32 + kb * 8;
    const int term = (t0 >= 144) ? 1 : 0;
    const int rem = t0 - term * 144;
    offs[j] = term * (int)PT + (rem >> 4) * PCOLS + (rem & 8);
  }

  v4f acc[4][4];
  #pragma unroll
  for (int m = 0; m < 4; ++m)
    #pragma unroll
    for (int n = 0; n < 4; ++n) acc[m][n] = (v4f){0.f, 0.f, 0.f, 0.f};

  #pragma unroll
  for (int j = 0; j < 9; ++j) {
    v8h av[4];
    #pragma unroll
    for (int m = 0; m < 4; ++m) {
      const void* ap = __builtin_assume_aligned(
          (const void*)(pb + offs[j] + m * 16), 4);
      uint4 tv;
      __builtin_memcpy(&tv, ap, 16);
      av[m] = __builtin_bit_cast(v8h, tv);
    }
    #pragma unroll
    for (int n = 0; n < 4; ++n) {
      const v8h bv = *(const v8h*)(wf + ((size_t)(j * 4 + n) * 64 + l) * 8);
      #pragma unroll
      for (int m = 0; m < 4; ++m)
        acc[m][n] = __builtin_amdgcn_mfma_f32_16x16x32_f16(av[m], bv, acc[m][n], 0, 0, 0);
    }
  }

  const float ws1 = scales[0];
  const float sc = s1[0], step = sc / 255.0f;
  unsigned char* orow = h1p + ((size_t)(b * HH + y) * WP + 2) * 64;
  #pragma unroll
  for (int n = 0; n < 4; ++n) {
    const int oc = n * 16 + r;
    const float bias = b1[oc];
    #pragma unroll
    for (int m = 0; m < 4; ++m) {
      #pragma unroll
      for (int reg = 0; reg < 4; ++reg) {
        const int px = pxw + m * 16 + kb * 4 + reg;
        const float h = acc[m][n][reg] * ws1 + bias;
        const float c = fminf(fmaxf(h, 0.0f), sc);
        int qi = (int)rintf(c / step);
        qi = qi < 0 ? 0 : (qi > 255 ? 255 : qi);
        orow[(size_t)px * 64 + oc] = (unsigned char)(qi ^ 0x80);
      }
    }
  }
}

// -------- conv2: implicit-GEMM int8 MFMA (unchanged) --------
__global__ __launch_bounds__(256) void conv2_k(
    const unsigned char* __restrict__ h1p,
    const int4* __restrict__ w2s,
    const int* __restrict__ corr2,
    const float* __restrict__ b2,
    const float* __restrict__ scales,
    const float* __restrict__ s1, const float* __restrict__ s2,
    unsigned char* __restrict__ h2p) {
  __shared__ alignas(16) signed char wlds[51200];
  __shared__ int clds[160];
  {
    int4* dst = (int4*)wlds;
    for (int i = threadIdx.x; i < 3200; i += 256) dst[i] = w2s[i];
    if (threadIdx.x < 160) clds[threadIdx.x] = corr2[threadIdx.x];
  }
  __syncthreads();

  const int lane = threadIdx.x & 63;
  const int wave = threadIdx.x >> 6;
  const int y = blockIdx.y, bz = blockIdx.z;
  const int xw = blockIdx.x * 256 + wave * 64;
  const int row = lane & 15, kb = lane >> 4;

  v4i acc[4][2];
  #pragma unroll
  for (int t = 0; t < 4; ++t)
    #pragma unroll
    for (int n = 0; n < 2; ++n) acc[t][n] = (v4i){0, 0, 0, 0};

  const size_t a_lane_off = (size_t)(xw + row) * 64 + kb * 16;
  const signed char* bl = wlds + kb * 512 + row * 16;

  #pragma unroll
  for (int ky = 0; ky < 5; ++ky) {
    const int yy = y + ky - 2;
    if (yy < 0 || yy >= HH) continue;
    const unsigned char* ap = h1p + ((size_t)(bz * HH + yy) * WP) * 64 + a_lane_off;
    const signed char* bt = bl + (ky * 5) * 2048;
    #pragma unroll
    for (int kx = 0; kx < 5; ++kx) {
      const v4i a0 = *(const v4i*)(ap + kx * 64);
      const v4i a1 = *(const v4i*)(ap + kx * 64 + 1024);
      const v4i a2 = *(const v4i*)(ap + kx * 64 + 2048);
      const v4i a3 = *(const v4i*)(ap + kx * 64 + 3072);
      const v4i bf0 = *(const v4i*)(bt + kx * 2048);
      const v4i bf1 = *(const v4i*)(bt + kx * 2048 + 256);
      acc[0][0] = __builtin_amdgcn_mfma_i32_16x16x64_i8(a0, bf0, acc[0][0], 0, 0, 0);
      acc[0][1] = __builtin_amdgcn_mfma_i32_16x16x64_i8(a0, bf1, acc[0][1], 0, 0, 0);
      acc[1][0] = __builtin_amdgcn_mfma_i32_16x16x64_i8(a1, bf0, acc[1][0], 0, 0, 0);
      acc[1][1] = __builtin_amdgcn_mfma_i32_16x16x64_i8(a1, bf1, acc[1][1], 0, 0, 0);
      acc[2][0] = __builtin_amdgcn_mfma_i32_16x16x64_i8(a2, bf0, acc[2][0], 0, 0, 0);
      acc[2][1] = __builtin_amdgcn_mfma_i32_16x16x64_i8(a2, bf1, acc[2][1], 0, 0, 0);
      acc[3][0] = __builtin_amdgcn_mfma_i32_16x16x64_i8(a3, bf0, acc[3][0], 0, 0, 0);
      acc[3][1] = __builtin_amdgcn_mfma_i32_16x16x64_i8(a3, bf1, acc[3][1], 0, 0, 0);
    }
  }

  int corr[2] = {0, 0};
  #pragma unroll
  for (int ky = 0; ky < 5; ++ky) {
    const int yy = y + ky - 2;
    if (yy >= 0 && yy < HH) {
      corr[0] += clds[ky * 32 + row];
      corr[1] += clds[ky * 32 + 16 + row];
    }
  }

  const float step1 = s1[0] / 255.0f;
  const float sc2 = s2[0], step2 = sc2 / 255.0f;
  const float asc = step1 * scales[1];
  unsigned char* orow = h2p + ((size_t)(bz * HH + y) * WP + 2) * 32;
  #pragma unroll
  for (int t = 0; t < 4; ++t) {
    #pragma unroll
    for (int n = 0; n < 2; ++n) {
      const int oc = n * 16 + row;
      const float bias = b2[oc];
      #pragma unroll
      for (int rr = 0; rr < 4; ++rr) {
        const int pix = xw + t * 16 + kb * 4 + rr;
        const float v = (float)(acc[t][n][rr] + corr[n] * 128) * asc + bias;
        const float c = fminf(fmaxf(v, 0.0f), sc2);
        int qi = (int)rintf(c / step2);
        qi = qi < 0 ? 0 : (qi > 255 ? 255 : qi);
        orow[(size_t)pix * 32 + oc] = (unsigned char)(qi ^ 0x80);
      }
    }
  }
}

// -------- conv3: NHWC + sdot4, exact int (unchanged) --------
__global__ __launch_bounds__(256) void conv3_k(
    const unsigned char* __restrict__ h2p,
    const signed char* __restrict__ w3p,
    const int* __restrict__ rowsum3,
    const float* __restrict__ b3,
    const float* __restrict__ scales,
    const float* __restrict__ s2, const float* __restrict__ s3,
    float* __restrict__ out) {
  const int p  = blockIdx.x * 256 + threadIdx.x;
  const int px = p & (WW - 1);
  const int py = (p >> 9) & (HH - 1);
  const int bz = p >> 18;

  int acc = 0, corr = 0;
  #pragma unroll
  for (int ky = 0; ky < 5; ++ky) {
    const int yy = py + ky - 2;
    if (yy < 0 || yy >= HH) continue;
    corr += rowsum3[ky];
    const unsigned char* rp = h2p + ((size_t)(bz * HH + yy) * WP + px) * 32;
    #pragma unroll
    for (int kx = 0; kx < 5; ++kx) {
      const int* ap = (const int*)(rp + kx * 32);
      const int* wp = (const int*)(w3p + (ky * 5 + kx) * 32);
      #pragma unroll
      for (int g = 0; g < 8; ++g) acc = DOT4(ap[g], wp[g], acc);
    }
  }

  const int tot = acc + corr * 128;
  const float step2 = s2[0] / 255.0f;
  const float sc3 = s3[0], step3 = sc3 / 255.0f;
  const float y = (float)tot * (step2 * scales[2]) + b3[0];
  const float c = fminf(fmaxf(y, 0.0f), sc3);
  float q = rintf(c / step3);
  q = fminf(fmaxf(q, 0.0f), 255.0f);
  out[p] = q * step3;
}

extern "C" void kernel_launch(void* const* d_in, const int* in_sizes, int n_in,
                              void* d_out, int out_size, void* d_ws, size_t ws_size,
                              hipStream_t stream) {
  const float* x  = (const float*)d_in[0];
  const float* w1 = (const float*)d_in[1];
  const float* b1 = (const float*)d_in[2];
  const float* w2 = (const float*)d_in[3];
  const float* b2 = (const float*)d_in[4];
  const float* w3 = (const float*)d_in[5];
  const float* b3 = (const float*)d_in[6];
  const float* s1 = (const float*)d_in[7];
  const float* s2 = (const float*)d_in[8];
  const float* s3 = (const float*)d_in[9];

  if (ws_size < WS_NEED) return;

  char* ws = (char*)d_ws;
  float*          scales  = (float*)(ws + SCALES_OFF);
  int*            corr2   = (int*)(ws + CORR2_OFF);
  int*            rowsum3 = (int*)(ws + RS3_OFF);
  float*          qw1     = (float*)(ws + QW1_OFF);
  unsigned short* w1frag  = (unsigned short*)(ws + W1FRAG_OFF);
  signed char*    w2s     = (signed char*)(ws + W2S_OFF);
  signed char*    w3p     = (signed char*)(ws + W3P_OFF);
  unsigned char*  h1p     = (unsigned char*)(ws + H1_OFF);
  unsigned char*  h2p     = (unsigned char*)(ws + H2_OFF);
  unsigned short* planes  = (unsigned short*)(ws + H2_OFF);  // overlaps h2p until conv2

  quant_weights_k<<<3, 256, 0, stream>>>(w1, w2, w3, scales, qw1, w2s, w3p);
  prep_k<<<1, 256, 0, stream>>>(w2s, w3p, qw1, corr2, rowsum3, w1frag);
  prep_x_k<<<(int)(PT / 256), 256, 0, stream>>>(x, planes);

  conv1_k<<<BB * HH, 512, 0, stream>>>(planes, w1frag, b1, scales, s1, h1p);
  fill_k<<<384, 256, 0, stream>>>(h1p, h2p);   // after conv1 (h2p region held planes)

  const int npix = BB * HH * WW;
  dim3 g2(2, HH, BB);
  conv2_k<<<g2, 256, 0, stream>>>(h1p, (const int4*)w2s, corr2, b2, scales, s1, s2, h2p);
  conv3_k<<<npix / 256, 256, 0, stream>>>(h2p, w3p, rowsum3, b3, scales, s2, s3, (float*)d_out);
}

// Round 4
// 429.214 us; speedup vs baseline: 12.8999x; 1.2855x over previous
//
#include <hip/hip_runtime.h>
#include <cmath>

#define HH 512
#define WW 512
#define BB 8
#define WP (WW + 4)    // padded row width (2-px halo each side)
#define HP (HH + 4)    // padded rows (2 zero-rows top/bottom)

#define PROWS 520      // x-plane rows: 512 + 4 top + 4 bottom
#define PCOLS 528      // x-plane cols: 512 + 4 left + 12 right (kx pad to 16)
#define PT ((size_t)BB * PROWS * PCOLS)

typedef int v4i __attribute__((ext_vector_type(4)));
typedef float v4f __attribute__((ext_vector_type(4)));
typedef _Float16 v8h __attribute__((ext_vector_type(8)));

#if defined(__has_builtin)
#if __has_builtin(__builtin_amdgcn_sdot4)
#define DOT4(a, b, c) __builtin_amdgcn_sdot4((a), (b), (c), false)
#endif
#endif
#ifndef DOT4
static __device__ __forceinline__ int dot4_fb(int a, int b, int c) {
  c += ((a << 24) >> 24) * ((b << 24) >> 24);
  c += ((a << 16) >> 24) * ((b << 16) >> 24);
  c += ((a << 8) >> 24) * ((b << 8) >> 24);
  c += (a >> 24) * (b >> 24);
  return c;
}
#define DOT4(a, b, c) dot4_fb((a), (b), (c))
#endif

// -------- workspace layout --------
static constexpr size_t SCALES_OFF = 0;        // float[3]
static constexpr size_t CORRF_OFF  = 64;       // int[32]  full-window corr, conv2
static constexpr size_t FS3_OFF    = 512;      // int[1]   full-window sum, conv3
static constexpr size_t QW1_OFF    = 1024;     // float[64*81]
static constexpr size_t W1FRAG_OFF = 24576;    // f16[9*4*64*8]
static constexpr size_t W2S_OFF    = 65536;    // i8[25*4*32*16]
static constexpr size_t W3P_OFF    = 131072;   // i8[25*32]
static constexpr size_t H1_OFF     = (size_t)1 << 20;
static constexpr size_t H1_SZ      = (size_t)BB * HP * WP * 64;   // 136.3 MB
static constexpr size_t H2_OFF     = H1_OFF + H1_SZ;
static constexpr size_t H2_SZ      = (size_t)BB * HP * WP * 32;   // 68.2 MB
static constexpr size_t WS_NEED    = H2_OFF + H2_SZ;
// x-planes (4*PT f16 = 17.6 MB) live in the h2p region until conv2 runs.

// -------- weight quantization --------
__global__ void quant_weights_k(const float* __restrict__ w1,
                                const float* __restrict__ w2,
                                const float* __restrict__ w3,
                                float* __restrict__ scales,
                                float* __restrict__ qw1,
                                signed char* __restrict__ w2s,
                                signed char* __restrict__ w3p) {
  const int t = blockIdx.x;
  const float* src = (t == 0) ? w1 : (t == 1) ? w2 : w3;
  const int n = (t == 0) ? 64 * 81 : (t == 1) ? 32 * 64 * 25 : 32 * 25;
  __shared__ float red[256];
  float m = 0.0f;
  for (int i = threadIdx.x; i < n; i += 256) m = fmaxf(m, fabsf(src[i]));
  red[threadIdx.x] = m;
  __syncthreads();
  for (int s = 128; s > 0; s >>= 1) {
    if ((int)threadIdx.x < s) red[threadIdx.x] = fmaxf(red[threadIdx.x], red[threadIdx.x + s]);
    __syncthreads();
  }
  const float scale = red[0] / 127.0f;
  if (threadIdx.x == 0) scales[t] = scale;
  for (int i = threadIdx.x; i < n; i += 256) {
    float q = rintf(src[i] / scale);
    q = fminf(fmaxf(q, -127.0f), 127.0f);
    if (t == 0) {
      qw1[i] = q;
    } else if (t == 1) {
      const int oc = i / 1600;
      const int r = i - oc * 1600;
      const int ic = r / 25, tap = r - ic * 25;
      w2s[(((tap * 4 + (ic >> 4)) * 32) + oc) * 16 + (ic & 15)] = (signed char)(int)q;
    } else {
      const int ic = i / 25, tap = i - ic * 25;
      w3p[tap * 32 + ic] = (signed char)(int)q;
    }
  }
}

// -------- prep: corrf / fs3 / conv1 B-fragments --------
__global__ void prep_k(const signed char* __restrict__ w2s,
                       const signed char* __restrict__ w3p,
                       const float* __restrict__ qw1,
                       int* __restrict__ corrf, int* __restrict__ fs3,
                       unsigned short* __restrict__ w1frag) {
  const int tid = threadIdx.x;
  if (tid < 32) {
    int s = 0;
    for (int tap = 0; tap < 25; ++tap)
      for (int kb = 0; kb < 4; ++kb)
        for (int j = 0; j < 16; ++j)
          s += (int)w2s[((tap * 4 + kb) * 32 + tid) * 16 + j];
    corrf[tid] = s;
  } else if (tid == 32) {
    int s = 0;
    for (int i = 0; i < 800; ++i) s += (int)w3p[i];
    fs3[0] = s;
  }
  for (int i = tid; i < 18432; i += 256) {
    const int e = i & 7, lidx = (i >> 3) & 63, nn = (i >> 9) & 3, j = i >> 11;
    const int t = j * 32 + (lidx >> 4) * 8 + e;
    const int term = (t >= 144) ? 1 : 0;
    const int rem = t - term * 144;
    const int ky = rem >> 4, kx = rem & 15;
    const int oc = nn * 16 + (lidx & 15);
    float v = 0.0f;
    if (kx < 9) v = qw1[oc * 81 + ky * 9 + kx];
    if (term) v *= (1.0f / 4096.0f);
    const _Float16 hv = (_Float16)v;
    w1frag[i] = __builtin_bit_cast(unsigned short, hv);
  }
}

// -------- prep x-planes: f16 hi/lo split, zero-padded, parity-duplicated --------
__global__ __launch_bounds__(256) void prep_x_k(const float* __restrict__ x,
                                                unsigned short* __restrict__ planes) {
  const size_t i = (size_t)blockIdx.x * 256 + threadIdx.x;
  if (i >= PT) return;
  const int col = (int)(i % PCOLS);
  const size_t t = i / PCOLS;
  const int row = (int)(t % PROWS);
  const int b = (int)(t / PROWS);
  const float* xb = x + (size_t)b * HH * WW;
  const int xr = row - 4;
  float v0 = 0.0f, v1 = 0.0f;
  if (xr >= 0 && xr < HH) {
    const int c0 = col - 4, c1 = col - 3;
    if (c0 >= 0 && c0 < WW) v0 = xb[(size_t)xr * WW + c0];
    if (c1 >= 0 && c1 < WW) v1 = xb[(size_t)xr * WW + c1];
  }
  const _Float16 h0 = (_Float16)v0;
  const _Float16 l0 = (_Float16)((v0 - (float)h0) * 4096.0f);
  const _Float16 h1 = (_Float16)v1;
  const _Float16 l1 = (_Float16)((v1 - (float)h1) * 4096.0f);
  planes[i]          = __builtin_bit_cast(unsigned short, h0);
  planes[PT + i]     = __builtin_bit_cast(unsigned short, l0);
  planes[2 * PT + i] = __builtin_bit_cast(unsigned short, h1);
  planes[3 * PT + i] = __builtin_bit_cast(unsigned short, l1);
}

// -------- fill borders of h1p/h2p with 0x80 (biased zero) --------
// h1 pad rows: 66048 u4 | h1 halo cols: 65536 | h2 pad rows: 33024 | h2 halo cols: 32768
__global__ void fill_k(unsigned char* __restrict__ h1p, unsigned char* __restrict__ h2p) {
  const int idx = blockIdx.x * 256 + threadIdx.x;
  const uint4 v = make_uint4(0x80808080u, 0x80808080u, 0x80808080u, 0x80808080u);
  if (idx < 66048) {
    const int q = idx & 3; const int u = idx >> 2;
    const int pxi = u % WP; const int rr = u / WP;
    const int bb = rr >> 2, sel = rr & 3;
    const int row = (sel < 2) ? sel : 512 + sel;
    *(uint4*)(h1p + (((size_t)bb * HP + row) * WP + pxi) * 64 + q * 16) = v;
  } else if (idx < 131584) {
    const int e = idx - 66048; const int q = e & 3; int u = e >> 2;
    const int c = u & 3; u >>= 2;
    const int row = 2 + (u & 511); const int bb = u >> 9;
    const int col = (c < 2) ? c : 512 + c;
    *(uint4*)(h1p + (((size_t)bb * HP + row) * WP + col) * 64 + q * 16) = v;
  } else if (idx < 164608) {
    const int e = idx - 131584; const int q = e & 1; const int u = e >> 1;
    const int pxi = u % WP; const int rr = u / WP;
    const int bb = rr >> 2, sel = rr & 3;
    const int row = (sel < 2) ? sel : 512 + sel;
    *(uint4*)(h2p + (((size_t)bb * HP + row) * WP + pxi) * 32 + q * 16) = v;
  } else {
    const int e = idx - 164608; const int q = e & 1; int u = e >> 1;
    const int c = u & 3; u >>= 2;
    const int row = 2 + (u & 511); const int bb = u >> 9;
    const int col = (c < 2) ? c : 512 + c;
    *(uint4*)(h2p + (((size_t)bb * HP + row) * WP + col) * 32 + q * 16) = v;
  }
}

// -------- conv1: f16-split implicit-GEMM MFMA, writes biased u8 NHWC (padded rows) ----
__global__ __launch_bounds__(512) void conv1_k(
    const unsigned short* __restrict__ planes,
    const unsigned short* __restrict__ w1frag,
    const float* __restrict__ b1,
    const float* __restrict__ scales,
    const float* __restrict__ s1,
    unsigned char* __restrict__ h1p) {
  __shared__ alignas(16) unsigned short wf[18432];
  for (int i = threadIdx.x; i < 2304; i += 512)
    ((int4*)wf)[i] = ((const int4*)w1frag)[i];
  __syncthreads();

  const int y = blockIdx.x & (HH - 1);
  const int b = blockIdx.x >> 9;
  const int l = threadIdx.x & 63;
  const int wv = threadIdx.x >> 6;
  const int pxw = wv * 64;
  const int r = l & 15, kb = l >> 4;

  const unsigned short* pb = planes + (size_t)(r & 1) * (2 * PT)
                           + ((size_t)b * PROWS + y) * PCOLS + (pxw + (r & ~1));
  int offs[9];
  #pragma unroll
  for (int j = 0; j < 9; ++j) {
    const int t0 = j * 32 + kb * 8;
    const int term = (t0 >= 144) ? 1 : 0;
    const int rem = t0 - term * 144;
    offs[j] = term * (int)PT + (rem >> 4) * PCOLS + (rem & 8);
  }

  v4f acc[4][4];
  #pragma unroll
  for (int m = 0; m < 4; ++m)
    #pragma unroll
    for (int n = 0; n < 4; ++n) acc[m][n] = (v4f){0.f, 0.f, 0.f, 0.f};

  #pragma unroll
  for (int j = 0; j < 9; ++j) {
    v8h av[4];
    #pragma unroll
    for (int m = 0; m < 4; ++m) {
      const void* ap = __builtin_assume_aligned((const void*)(pb + offs[j] + m * 16), 4);
      uint4 tv;
      __builtin_memcpy(&tv, ap, 16);
      av[m] = __builtin_bit_cast(v8h, tv);
    }
    #pragma unroll
    for (int n = 0; n < 4; ++n) {
      const v8h bv = *(const v8h*)(wf + ((size_t)(j * 4 + n) * 64 + l) * 8);
      #pragma unroll
      for (int m = 0; m < 4; ++m)
        acc[m][n] = __builtin_amdgcn_mfma_f32_16x16x32_f16(av[m], bv, acc[m][n], 0, 0, 0);
    }
  }

  const float ws1 = scales[0];
  const float sc = s1[0], step = sc / 255.0f;
  unsigned char* orow = h1p + (((size_t)b * HP + y + 2) * WP + 2) * 64;
  #pragma unroll
  for (int n = 0; n < 4; ++n) {
    const int oc = n * 16 + r;
    const float bias = b1[oc];
    #pragma unroll
    for (int m = 0; m < 4; ++m) {
      #pragma unroll
      for (int reg = 0; reg < 4; ++reg) {
        const int px = pxw + m * 16 + kb * 4 + reg;
        const float h = acc[m][n][reg] * ws1 + bias;
        const float c = fminf(fmaxf(h, 0.0f), sc);
        int qi = (int)rintf(c / step);
        qi = qi < 0 ? 0 : (qi > 255 ? 255 : qi);
        orow[(size_t)px * 64 + oc] = (unsigned char)(qi ^ 0x80);
      }
    }
  }
}

// -------- conv2: int8 MFMA, 4-row wave tiles, row-fragment reuse, kx-prefetch --------
// block = 4 waves x (4 rows x 16 px) = 64 px x 4 rows; zero-padded rows -> no branches
__global__ __launch_bounds__(256) void conv2_k(
    const unsigned char* __restrict__ h1p,
    const int4* __restrict__ w2s,
    const int* __restrict__ corrf,
    const float* __restrict__ b2,
    const float* __restrict__ scales,
    const float* __restrict__ s1, const float* __restrict__ s2,
    unsigned char* __restrict__ h2p) {
  __shared__ alignas(16) signed char wlds[51200];
  __shared__ int clds[32];
  {
    int4* dst = (int4*)wlds;
    for (int i = threadIdx.x; i < 3200; i += 256) dst[i] = w2s[i];
    if (threadIdx.x < 32) clds[threadIdx.x] = corrf[threadIdx.x];
  }
  __syncthreads();

  const int l = threadIdx.x & 63;
  const int wv = threadIdx.x >> 6;
  const int r = l & 15, kb = l >> 4;
  const int y = blockIdx.y * 4;
  const int b = blockIdx.z;
  const int xw = blockIdx.x * 64 + wv * 16;

  v4i acc[4][2];
  #pragma unroll
  for (int t = 0; t < 4; ++t)
    #pragma unroll
    for (int n = 0; n < 2; ++n) acc[t][n] = (v4i){0, 0, 0, 0};

  const size_t rstride = (size_t)WP * 64;
  const unsigned char* abase = h1p + (((size_t)b * HP + y) * WP + xw + r) * 64 + kb * 16;

  v4i a_cur[8], a_nxt[8];
  #pragma unroll
  for (int j = 0; j < 8; ++j) a_cur[j] = *(const v4i*)(abase + j * rstride);

  #pragma unroll
  for (int kx = 0; kx < 5; ++kx) {
    if (kx < 4) {
      #pragma unroll
      for (int j = 0; j < 8; ++j)
        a_nxt[j] = *(const v4i*)(abase + (kx + 1) * 64 + j * rstride);
    }
    const signed char* bcol = wlds + kx * 2048 + kb * 512 + r * 16;
    #pragma unroll
    for (int ky = 0; ky < 5; ++ky) {
      const v4i bf0 = *(const v4i*)(bcol + ky * 10240);
      const v4i bf1 = *(const v4i*)(bcol + ky * 10240 + 256);
      #pragma unroll
      for (int t = 0; t < 4; ++t) {
        acc[t][0] = __builtin_amdgcn_mfma_i32_16x16x64_i8(a_cur[ky + t], bf0, acc[t][0], 0, 0, 0);
        acc[t][1] = __builtin_amdgcn_mfma_i32_16x16x64_i8(a_cur[ky + t], bf1, acc[t][1], 0, 0, 0);
      }
    }
    if (kx < 4) {
      #pragma unroll
      for (int j = 0; j < 8; ++j) a_cur[j] = a_nxt[j];
    }
  }

  const float step1 = s1[0] / 255.0f;
  const float sc2 = s2[0], step2 = sc2 / 255.0f;
  const float asc = step1 * scales[1];
  #pragma unroll
  for (int n = 0; n < 2; ++n) {
    const int oc = n * 16 + r;
    const float bias = b2[oc];
    const int c128 = clds[oc] * 128;
    #pragma unroll
    for (int t = 0; t < 4; ++t) {
      unsigned char* orow = h2p + (((size_t)b * HP + y + t + 2) * WP + xw + 2) * 32;
      #pragma unroll
      for (int reg = 0; reg < 4; ++reg) {
        const int pxi = kb * 4 + reg;
        const float v = (float)(acc[t][n][reg] + c128) * asc + bias;
        const float c = fminf(fmaxf(v, 0.0f), sc2);
        int qi = (int)rintf(c / step2);
        qi = qi < 0 ? 0 : (qi > 255 ? 255 : qi);
        orow[(size_t)pxi * 32 + oc] = (unsigned char)(qi ^ 0x80);
      }
    }
  }
}

// -------- conv3: NHWC + sdot4, padded rows -> branch-free --------
__global__ __launch_bounds__(256) void conv3_k(
    const unsigned char* __restrict__ h2p,
    const signed char* __restrict__ w3p,
    const int* __restrict__ fs3,
    const float* __restrict__ b3,
    const float* __restrict__ scales,
    const float* __restrict__ s2, const float* __restrict__ s3,
    float* __restrict__ out) {
  const int p  = blockIdx.x * 256 + threadIdx.x;
  const int px = p & (WW - 1);
  const int py = (p >> 9) & (HH - 1);
  const int bz = p >> 18;

  int acc = 0;
  const unsigned char* base = h2p + (((size_t)bz * HP + py) * WP + px) * 32;
  #pragma unroll
  for (int ky = 0; ky < 5; ++ky) {
    const unsigned char* rp = base + (size_t)ky * WP * 32;
    #pragma unroll
    for (int kx = 0; kx < 5; ++kx) {
      const int* ap = (const int*)(rp + kx * 32);
      const int* wp = (const int*)(w3p + (ky * 5 + kx) * 32);
      #pragma unroll
      for (int g = 0; g < 8; ++g) acc = DOT4(ap[g], wp[g], acc);
    }
  }

  const int tot = acc + fs3[0] * 128;
  const float step2 = s2[0] / 255.0f;
  const float sc3 = s3[0], step3 = sc3 / 255.0f;
  const float y = (float)tot * (step2 * scales[2]) + b3[0];
  const float c = fminf(fmaxf(y, 0.0f), sc3);
  float q = rintf(c / step3);
  q = fminf(fmaxf(q, 0.0f), 255.0f);
  out[p] = q * step3;
}

extern "C" void kernel_launch(void* const* d_in, const int* in_sizes, int n_in,
                              void* d_out, int out_size, void* d_ws, size_t ws_size,
                              hipStream_t stream) {
  const float* x  = (const float*)d_in[0];
  const float* w1 = (const float*)d_in[1];
  const float* b1 = (const float*)d_in[2];
  const float* w2 = (const float*)d_in[3];
  const float* b2 = (const float*)d_in[4];
  const float* w3 = (const float*)d_in[5];
  const float* b3 = (const float*)d_in[6];
  const float* s1 = (const float*)d_in[7];
  const float* s2 = (const float*)d_in[8];
  const float* s3 = (const float*)d_in[9];

  if (ws_size < WS_NEED) return;

  char* ws = (char*)d_ws;
  float*          scales  = (float*)(ws + SCALES_OFF);
  int*            corrf   = (int*)(ws + CORRF_OFF);
  int*            fs3     = (int*)(ws + FS3_OFF);
  float*          qw1     = (float*)(ws + QW1_OFF);
  unsigned short* w1frag  = (unsigned short*)(ws + W1FRAG_OFF);
  signed char*    w2s     = (signed char*)(ws + W2S_OFF);
  signed char*    w3p     = (signed char*)(ws + W3P_OFF);
  unsigned char*  h1p     = (unsigned char*)(ws + H1_OFF);
  unsigned char*  h2p     = (unsigned char*)(ws + H2_OFF);
  unsigned short* planes  = (unsigned short*)(ws + H2_OFF);  // overlaps h2p until conv2

  quant_weights_k<<<3, 256, 0, stream>>>(w1, w2, w3, scales, qw1, w2s, w3p);
  prep_k<<<1, 256, 0, stream>>>(w2s, w3p, qw1, corrf, fs3, w1frag);
  prep_x_k<<<(int)(PT / 256), 256, 0, stream>>>(x, planes);

  conv1_k<<<BB * HH, 512, 0, stream>>>(planes, w1frag, b1, scales, s1, h1p);
  fill_k<<<771, 256, 0, stream>>>(h1p, h2p);   // after conv1 (h2p region held planes)

  dim3 g2(8, 128, BB);
  conv2_k<<<g2, 256, 0, stream>>>(h1p, (const int4*)w2s, corrf, b2, scales, s1, s2, h2p);

  const int npix = BB * HH * WW;
  conv3_k<<<npix / 256, 256, 0, stream>>>(h2p, w3p, fs3, b3, scales, s2, s3, (float*)d_out);
}